// Round 1
// baseline (262.621 us; speedup 1.0000x reference)
//
#include <hip/hip_runtime.h>

#define NSYS 64
#define NAT  1000
#define NTOT (NSYS * NAT)          // 64000
#define MP   2200000               // MAX_PAIRS
#define CUT2 25.0f                 // cutoff^2
#define PADV 64000.0f              // padding_value = n

// Identical distance expression in count & write passes (must match bit-exactly
// so row offsets stay consistent).
__device__ __forceinline__ float dist2f(float xi, float yi, float zi,
                                        float xj, float yj, float zj) {
    float dx = xi - xj, dy = yi - yj, dz = zi - zj;
    return fmaf(dz, dz, fmaf(dy, dy, dx * dx));
}

// AoS (64000,3) -> SoA xs/ys/zs for coalesced j-stream loads.
__global__ void k_transpose(const float* __restrict__ c,
                            float* __restrict__ xs, float* __restrict__ ys,
                            float* __restrict__ zs) {
    int a = blockIdx.x * blockDim.x + threadIdx.x;
    if (a < NTOT) {
        xs[a] = c[3 * a + 0];
        ys[a] = c[3 * a + 1];
        zs[a] = c[3 * a + 2];
    }
}

// One wave (64 lanes) per row (s,i): count kept pairs j in (i, NAT).
__global__ void k_count(const float* __restrict__ xs, const float* __restrict__ ys,
                        const float* __restrict__ zs, int* __restrict__ counts) {
    int gt   = blockIdx.x * blockDim.x + threadIdx.x;
    int row  = gt >> 6;
    int lane = threadIdx.x & 63;
    if (row >= NTOT) return;
    int i       = row % NAT;
    int rowbase = row - i;                       // s*NAT
    float xi = xs[row], yi = ys[row], zi = zs[row];
    int cnt = 0;
    for (int j0 = i + 1; j0 < NAT; j0 += 64) {   // j0 wave-uniform
        int j = j0 + lane;
        if (j < NAT) {
            int b = rowbase + j;
            float d2 = dist2f(xi, yi, zi, xs[b], ys[b], zs[b]);
            cnt += (d2 < CUT2) ? 1 : 0;
        }
    }
    for (int off = 32; off > 0; off >>= 1) cnt += __shfl_xor(cnt, off, 64);
    if (lane == 0) counts[row] = cnt;
}

// Single-block exclusive scan over 64000 row counts (in place) + total.
__global__ void k_scan(int* __restrict__ counts, int* __restrict__ total) {
    __shared__ int lsum[1024];
    const int per = (NTOT + 1023) / 1024;        // 63
    int t    = threadIdx.x;
    int base = t * per;
    int s = 0;
    for (int k = 0; k < per; k++) {
        int r = base + k;
        if (r < NTOT) s += counts[r];
    }
    lsum[t] = s;
    __syncthreads();
    for (int off = 1; off < 1024; off <<= 1) {   // Hillis-Steele inclusive scan
        int v = (t >= off) ? lsum[t - off] : 0;
        __syncthreads();
        lsum[t] += v;
        __syncthreads();
    }
    int run = (t == 0) ? 0 : lsum[t - 1];        // exclusive prefix for my chunk
    for (int k = 0; k < per; k++) {
        int r = base + k;
        if (r < NTOT) {
            int c = counts[r];
            counts[r] = run;                     // counts[] becomes offsets[]
            run += c;
        }
    }
    if (t == 1023) *total = lsum[1023];
}

// One wave per row: recompute keep mask, write pairs at offset + ordered rank.
// Out layout (floats): [0,MP) src | [MP,2MP) dst | [2MP,3MP) dst | [3MP,4MP) src
//                      | [4MP,5MP) d12 | [5MP,6MP) d12 | [6MP] npairs
__global__ void k_write(const float* __restrict__ xs, const float* __restrict__ ys,
                        const float* __restrict__ zs, const int* __restrict__ offsets,
                        float* __restrict__ out) {
    int gt   = blockIdx.x * blockDim.x + threadIdx.x;
    int row  = gt >> 6;
    int lane = threadIdx.x & 63;
    if (row >= NTOT) return;
    int i       = row % NAT;
    int rowbase = row - i;
    float xi = xs[row], yi = ys[row], zi = zs[row];
    int running = offsets[row];
    unsigned long long lanemask = (1ull << lane) - 1ull;
    for (int j0 = i + 1; j0 < NAT; j0 += 64) {
        int j = j0 + lane;
        bool keep = false;
        float d2  = 0.0f;
        int   b   = rowbase + j;
        if (j < NAT) {
            d2   = dist2f(xi, yi, zi, xs[b], ys[b], zs[b]);
            keep = (d2 < CUT2);
        }
        unsigned long long m = __ballot(keep);
        if (keep) {
            int pos = running + (int)__popcll(m & lanemask);
            if (pos < MP) {
                float fs = (float)row;           // s*NAT + i
                float fd = (float)b;             // s*NAT + j
                out[pos]          = fs;
                out[MP + pos]     = fd;
                out[2 * MP + pos] = fd;
                out[3 * MP + pos] = fs;
                out[4 * MP + pos] = d2;
                out[5 * MP + pos] = d2;
            }
        }
        running += (int)__popcll(m);
    }
}

// Fill padding region [min(total,MP), MP) and write npairs.
__global__ void k_pad(const int* __restrict__ total_p, float* __restrict__ out) {
    int k = blockIdx.x * blockDim.x + threadIdx.x;
    int total = *total_p;
    if (k == 0) out[6 * MP] = (float)total;      // npairs (unclamped count)
    int valid = total < MP ? total : MP;
    if (k >= valid && k < MP) {
        out[k]          = PADV;
        out[MP + k]     = PADV;
        out[2 * MP + k] = PADV;
        out[3 * MP + k] = PADV;
        out[4 * MP + k] = CUT2;
        out[5 * MP + k] = CUT2;
    }
}

extern "C" void kernel_launch(void* const* d_in, const int* in_sizes, int n_in,
                              void* d_out, int out_size, void* d_ws, size_t ws_size,
                              hipStream_t stream) {
    const float* coords = (const float*)d_in[0];
    float* out = (float*)d_out;

    // Workspace layout: counts/offsets [64000 ints] | total [1 int, +pad] | SoA xyz
    int*   counts = (int*)d_ws;
    int*   total  = counts + NTOT;
    float* xs     = (float*)(counts + NTOT + 16);
    float* ys     = xs + NTOT;
    float* zs     = ys + NTOT;

    k_transpose<<<(NTOT + 255) / 256, 256, 0, stream>>>(coords, xs, ys, zs);
    k_count<<<(NTOT * 64) / 256, 256, 0, stream>>>(xs, ys, zs, counts);
    k_scan<<<1, 1024, 0, stream>>>(counts, total);
    k_write<<<(NTOT * 64) / 256, 256, 0, stream>>>(xs, ys, zs, counts, out);
    k_pad<<<(MP + 255) / 256, 256, 0, stream>>>(total, out);
}

// Round 2
// 148.108 us; speedup vs baseline: 1.7732x; 1.7732x over previous
//
#include <hip/hip_runtime.h>

#define NSYS 64
#define NAT  1000
#define NTOT (NSYS * NAT)          // 64000
#define MP   2200000               // MAX_PAIRS
#define CUT2 25.0f                 // cutoff^2
#define PADV 64000.0f              // padding_value = n
#define SCAN_BLOCKS 250            // 250 * 256 == 64000 exactly

// Identical distance expression in count & write passes (must match bit-exactly
// so row offsets stay consistent).
__device__ __forceinline__ float dist2f(float xi, float yi, float zi,
                                        float xj, float yj, float zj) {
    float dx = xi - xj, dy = yi - yj, dz = zi - zj;
    return fmaf(dz, dz, fmaf(dy, dy, dx * dx));
}

// AoS (64000,3) -> SoA xs/ys/zs for coalesced j-stream loads.
__global__ void k_transpose(const float* __restrict__ c,
                            float* __restrict__ xs, float* __restrict__ ys,
                            float* __restrict__ zs) {
    int a = blockIdx.x * blockDim.x + threadIdx.x;
    if (a < NTOT) {
        xs[a] = c[3 * a + 0];
        ys[a] = c[3 * a + 1];
        zs[a] = c[3 * a + 2];
    }
}

// One wave (64 lanes) per row (s,i): count kept pairs j in (i, NAT).
__global__ void k_count(const float* __restrict__ xs, const float* __restrict__ ys,
                        const float* __restrict__ zs, int* __restrict__ counts) {
    int gt   = blockIdx.x * blockDim.x + threadIdx.x;
    int row  = gt >> 6;
    int lane = threadIdx.x & 63;
    if (row >= NTOT) return;
    int i       = row % NAT;
    int rowbase = row - i;                       // s*NAT
    float xi = xs[row], yi = ys[row], zi = zs[row];
    int cnt = 0;
    for (int j0 = i + 1; j0 < NAT; j0 += 64) {   // j0 wave-uniform
        int j = j0 + lane;
        if (j < NAT) {
            int b = rowbase + j;
            float d2 = dist2f(xi, yi, zi, xs[b], ys[b], zs[b]);
            cnt += (d2 < CUT2) ? 1 : 0;
        }
    }
    for (int off = 32; off > 0; off >>= 1) cnt += __shfl_xor(cnt, off, 64);
    if (lane == 0) counts[row] = cnt;
}

// Level-1 scan: 250 blocks x 256 rows. In-place block-exclusive values,
// plus one block sum per block.
__global__ void k_scan_a(int* __restrict__ counts, int* __restrict__ bsum) {
    __shared__ int tmp[256];
    int t = threadIdx.x;
    int g = blockIdx.x * 256 + t;                // exact coverage, no bounds check
    int v = counts[g];
    tmp[t] = v;
    __syncthreads();
    for (int off = 1; off < 256; off <<= 1) {    // Hillis-Steele inclusive
        int u = (t >= off) ? tmp[t - off] : 0;
        __syncthreads();
        tmp[t] += u;
        __syncthreads();
    }
    counts[g] = tmp[t] - v;                      // exclusive within block
    if (t == 255) bsum[blockIdx.x] = tmp[255];
}

// Level-2 scan: one block scans the 250 block sums (in place, exclusive),
// writes grand total.
__global__ void k_scan_b(int* __restrict__ bsum, int* __restrict__ total) {
    __shared__ int tmp[256];
    int t = threadIdx.x;
    int v = (t < SCAN_BLOCKS) ? bsum[t] : 0;
    tmp[t] = v;
    __syncthreads();
    for (int off = 1; off < 256; off <<= 1) {
        int u = (t >= off) ? tmp[t - off] : 0;
        __syncthreads();
        tmp[t] += u;
        __syncthreads();
    }
    if (t < SCAN_BLOCKS) bsum[t] = tmp[t] - v;   // exclusive
    if (t == 255) *total = tmp[255];
}

// One wave per row: recompute keep mask, write pairs at offset + ordered rank.
// Out layout (floats): [0,MP) src | [MP,2MP) dst | [2MP,3MP) dst | [3MP,4MP) src
//                      | [4MP,5MP) d12 | [5MP,6MP) d12 | [6MP] npairs
__global__ void k_write(const float* __restrict__ xs, const float* __restrict__ ys,
                        const float* __restrict__ zs, const int* __restrict__ offsets,
                        const int* __restrict__ bsum, float* __restrict__ out) {
    int gt   = blockIdx.x * blockDim.x + threadIdx.x;
    int row  = gt >> 6;
    int lane = threadIdx.x & 63;
    if (row >= NTOT) return;
    int i       = row % NAT;
    int rowbase = row - i;
    float xi = xs[row], yi = ys[row], zi = zs[row];
    int running = offsets[row] + bsum[row >> 8]; // global exclusive prefix
    unsigned long long lanemask = (1ull << lane) - 1ull;
    for (int j0 = i + 1; j0 < NAT; j0 += 64) {
        int j = j0 + lane;
        bool keep = false;
        float d2  = 0.0f;
        int   b   = rowbase + j;
        if (j < NAT) {
            d2   = dist2f(xi, yi, zi, xs[b], ys[b], zs[b]);
            keep = (d2 < CUT2);
        }
        unsigned long long m = __ballot(keep);
        if (keep) {
            int pos = running + (int)__popcll(m & lanemask);
            if (pos < MP) {
                float fs = (float)row;           // s*NAT + i
                float fd = (float)b;             // s*NAT + j
                out[pos]          = fs;
                out[MP + pos]     = fd;
                out[2 * MP + pos] = fd;
                out[3 * MP + pos] = fs;
                out[4 * MP + pos] = d2;
                out[5 * MP + pos] = d2;
            }
        }
        running += (int)__popcll(m);
    }
}

// Fill padding region [min(total,MP), MP) and write npairs.
__global__ void k_pad(const int* __restrict__ total_p, float* __restrict__ out) {
    int k = blockIdx.x * blockDim.x + threadIdx.x;
    int total = *total_p;
    if (k == 0) out[6 * MP] = (float)total;      // npairs (unclamped count)
    int valid = total < MP ? total : MP;
    if (k >= valid && k < MP) {
        out[k]          = PADV;
        out[MP + k]     = PADV;
        out[2 * MP + k] = PADV;
        out[3 * MP + k] = PADV;
        out[4 * MP + k] = CUT2;
        out[5 * MP + k] = CUT2;
    }
}

extern "C" void kernel_launch(void* const* d_in, const int* in_sizes, int n_in,
                              void* d_out, int out_size, void* d_ws, size_t ws_size,
                              hipStream_t stream) {
    const float* coords = (const float*)d_in[0];
    float* out = (float*)d_out;

    // Workspace layout: counts [64000 ints] | bsum [256 ints] | total [1 int,
    // padded to 16] | SoA xyz
    int*   counts = (int*)d_ws;
    int*   bsum   = counts + NTOT;
    int*   total  = bsum + 256;
    float* xs     = (float*)(total + 16);
    float* ys     = xs + NTOT;
    float* zs     = ys + NTOT;

    k_transpose<<<(NTOT + 255) / 256, 256, 0, stream>>>(coords, xs, ys, zs);
    k_count<<<(NTOT * 64) / 256, 256, 0, stream>>>(xs, ys, zs, counts);
    k_scan_a<<<SCAN_BLOCKS, 256, 0, stream>>>(counts, bsum);
    k_scan_b<<<1, 256, 0, stream>>>(bsum, total);
    k_write<<<(NTOT * 64) / 256, 256, 0, stream>>>(xs, ys, zs, counts, bsum, out);
    k_pad<<<(MP + 255) / 256, 256, 0, stream>>>(total, out);
}